// Round 2
// baseline (662.283 us; speedup 1.0000x reference)
//
#include <hip/hip_runtime.h>
#include <cstddef>

#define LL 512
#define CC 32
#define NF1D 46
#define NF2D 44
#define KK 64
#define ROWP 520
#define HOFF 4

__device__ __forceinline__ float elu1(float a) {
    return a > 0.f ? a : (expf(a) - 1.f);
}

// select float t from a float4 window array with compile-time index
#define CF(c, t) ((t & 3) == 0 ? c[(t) >> 2].x : ((t & 3) == 1 ? c[(t) >> 2].y : ((t & 3) == 2 ? c[(t) >> 2].z : c[(t) >> 2].w)))

// conv3: z[32] = conv(src) for lane's (oc, seg): output positions l0..l0+31
__device__ __forceinline__ void conv32(const float* __restrict__ src,
                                       const float* __restrict__ wl,
                                       int oc, int l0, float z[32]) {
#pragma unroll
    for (int p = 0; p < 32; ++p) z[p] = 0.f;
#pragma unroll 2
    for (int ic = 0; ic < 32; ++ic) {
        const float* row = src + ic * ROWP + HOFF + l0 - 4;
        float4 c[10];
#pragma unroll
        for (int q = 0; q < 10; ++q) c[q] = *(const float4*)(row + 4 * q);
        float w0 = wl[(ic * 3 + 0) * 32 + oc];
        float w1 = wl[(ic * 3 + 1) * 32 + oc];
        float w2 = wl[(ic * 3 + 2) * 32 + oc];
#pragma unroll
        for (int p = 0; p < 32; ++p) {
            z[p] = fmaf(CF(c, (3 + p)), w0,
                   fmaf(CF(c, (4 + p)), w1,
                   fmaf(CF(c, (5 + p)), w2, z[p])));
        }
    }
}

// ---------------- fused tower kernel: 1 block per bt ----------------
// 512 threads: oc = tid&31, seg = tid>>5 (16 segs x 32 positions).
// x, y resident in LDS [32 ch][520] (halo-padded, zeroed). Stats via shfl+LDS tree.
__global__ __launch_bounds__(512) void tower_kernel(
    const float* __restrict__ t1d, const float* __restrict__ w1d,
    const float* __restrict__ b1d, const float* __restrict__ c1w,
    const float* __restrict__ c2w, const float* __restrict__ proj_w,
    const float* __restrict__ proj_b, float* __restrict__ lpe,
    float* __restrict__ rpe)
{
    __shared__ float xs[32 * ROWP];
    __shared__ float ys[32 * ROWP];
    __shared__ float wl[3072];
    __shared__ float redS[256], redQ[256];
    __shared__ float mvs[64];

    const int tid = threadIdx.x;
    const int oc = tid & 31;
    const int seg = tid >> 5;
    const int l0 = seg * 32;
    const int wv = tid >> 6;
    const int lane = tid & 63;
    const int bt = blockIdx.x;

    // zero halos (cols 0..3 and 516..519 of every row, both arrays)
    if (tid < 256) {
        int rr = tid >> 3, c8 = tid & 7;
        int col = c8 < 4 ? c8 : (ROWP - 8 + c8);
        xs[rr * ROWP + col] = 0.f;
        ys[rr * ROWP + col] = 0.f;
    }

    // ---- initial projection: x[oc][l] = sum_f t1d[bt,l,f] * w1d[oc,f] + b ----
    {
        float wp[46];
#pragma unroll
        for (int f = 0; f < 46; ++f) wp[f] = w1d[oc * 46 + f];
        float bb = b1d[oc];
        const float* tb = t1d + ((size_t)bt * LL + l0) * NF1D;
        for (int p = 0; p < 32; ++p) {
            const float2* rr = (const float2*)(tb + p * NF1D);
            float a = bb;
#pragma unroll
            for (int f2 = 0; f2 < 23; ++f2) {
                float2 v = rr[f2];
                a = fmaf(v.x, wp[2 * f2], a);
                a = fmaf(v.y, wp[2 * f2 + 1], a);
            }
            xs[oc * ROWP + HOFF + l0 + p] = a;
        }
    }

    float z[32];
    for (int rb = 0; rb < 4; ++rb) {
        // stage conv1 weights
        {
            const float* cw = c1w + rb * 3072;
            for (int t = tid; t < 3072; t += 512) {
                int o2 = t / 96, rem = t - o2 * 96;
                wl[rem * 32 + o2] = cw[t];
            }
        }
        __syncthreads();   // xs + wl ready

        conv32(xs, wl, oc, l0, z);

        // stats of raw conv1 output
        {
            float s = 0.f, q = 0.f;
#pragma unroll
            for (int p = 0; p < 32; ++p) { s += z[p]; q = fmaf(z[p], z[p], q); }
            s += __shfl_xor(s, 32);
            q += __shfl_xor(q, 32);
            if (lane < 32) { redS[wv * 32 + oc] = s; redQ[wv * 32 + oc] = q; }
        }
        __syncthreads();
        if (tid < 32) {
            float S = 0.f, Q = 0.f;
#pragma unroll
            for (int w8 = 0; w8 < 8; ++w8) { S += redS[w8 * 32 + tid]; Q += redQ[w8 * 32 + tid]; }
            float m = S * (1.0f / 512.0f);
            float v = Q * (1.0f / 512.0f) - m * m;
            mvs[tid] = m;
            mvs[32 + tid] = rsqrtf(v + 1e-5f);
        }
        __syncthreads();
        {
            float m = mvs[oc], inv = mvs[32 + oc];
            float* yr = ys + oc * ROWP + HOFF + l0;
#pragma unroll
            for (int p8 = 0; p8 < 8; ++p8) {
                float4 o4;
                o4.x = elu1((z[4 * p8 + 0] - m) * inv);
                o4.y = elu1((z[4 * p8 + 1] - m) * inv);
                o4.z = elu1((z[4 * p8 + 2] - m) * inv);
                o4.w = elu1((z[4 * p8 + 3] - m) * inv);
                *(float4*)(yr + 4 * p8) = o4;
            }
        }
        // stage conv2 weights (wl free: all conv1 reads done before stats barrier)
        {
            const float* cw = c2w + rb * 3072;
            for (int t = tid; t < 3072; t += 512) {
                int o2 = t / 96, rem = t - o2 * 96;
                wl[rem * 32 + o2] = cw[t];
            }
        }
        __syncthreads();   // ys + wl ready

        conv32(ys, wl, oc, l0, z);

        {
            float s = 0.f, q = 0.f;
#pragma unroll
            for (int p = 0; p < 32; ++p) { s += z[p]; q = fmaf(z[p], z[p], q); }
            s += __shfl_xor(s, 32);
            q += __shfl_xor(q, 32);
            if (lane < 32) { redS[wv * 32 + oc] = s; redQ[wv * 32 + oc] = q; }
        }
        __syncthreads();
        if (tid < 32) {
            float S = 0.f, Q = 0.f;
#pragma unroll
            for (int w8 = 0; w8 < 8; ++w8) { S += redS[w8 * 32 + tid]; Q += redQ[w8 * 32 + tid]; }
            float m = S * (1.0f / 512.0f);
            float v = Q * (1.0f / 512.0f) - m * m;
            mvs[tid] = m;
            mvs[32 + tid] = rsqrtf(v + 1e-5f);
        }
        __syncthreads();
        {
            float m = mvs[oc], inv = mvs[32 + oc];
            float* xr = xs + oc * ROWP + HOFF + l0;
#pragma unroll
            for (int p8 = 0; p8 < 8; ++p8) {
                float4 g = *(const float4*)(xr + 4 * p8);
                float4 o4;
                o4.x = elu1(g.x + (z[4 * p8 + 0] - m) * inv);
                o4.y = elu1(g.y + (z[4 * p8 + 1] - m) * inv);
                o4.z = elu1(g.z + (z[4 * p8 + 2] - m) * inv);
                o4.w = elu1(g.w + (z[4 * p8 + 3] - m) * inv);
                *(float4*)(xr + 4 * p8) = o4;
            }
        }
        __syncthreads();   // xs coherent for next rb / epilogue
    }

    // ---- epilogue: emb (= xs) -> lpe/rpe with pe + bias folded ----
    {
        const float C16 = 0.5756462732485115f;  // ln(10000)/16
        int o = tid & 63;
        int lg = tid >> 6;     // 0..7, each covers 64 l
        float Wl[32], Wr[32];
#pragma unroll
        for (int c = 0; c < 32; ++c) {
            Wl[c] = proj_w[o * 109 + NF2D + c];
            Wr[c] = proj_w[o * 109 + NF2D + 32 + c];
        }
        float wb = proj_b[o];
        float freq = expf(-(float)(o & 15) * C16);
        bool isSin = (o & 31) < 16;
        for (int lc = 0; lc < 32; ++lc) {
            int l = lg * 64 + lc * 2;
            float2 e[32];
#pragma unroll
            for (int c = 0; c < 32; ++c)
                e[c] = *(const float2*)&xs[c * ROWP + HOFF + l];
            float la0 = 0.f, la1 = 0.f, ra0 = wb, ra1 = wb;
#pragma unroll
            for (int c = 0; c < 32; ++c) {
                la0 = fmaf(e[c].x, Wl[c], la0);
                la1 = fmaf(e[c].y, Wl[c], la1);
                ra0 = fmaf(e[c].x, Wr[c], ra0);
                ra1 = fmaf(e[c].y, Wr[c], ra1);
            }
            if (bt == 0) {
                float a0 = (float)l * freq, a1 = (float)(l + 1) * freq;
                float p0 = isSin ? sinf(a0) : cosf(a0);
                float p1 = isSin ? sinf(a1) : cosf(a1);
                if (o < 32) { la0 += p0; la1 += p1; }
                else        { ra0 += p0; ra1 += p1; }
            }
            size_t r = (size_t)(bt * LL + l) * 64 + o;
            lpe[r] = la0; lpe[r + 64] = la1;
            rpe[r] = ra0; rpe[r + 64] = ra1;
        }
    }
}

// ---------------- pair kernel: 32-j tiles, 16 waves/CU, rolling prefetch ----------------
// block = (bt,i); wave owns 128 j as 4 tiles of 32; no __syncthreads in main loop.
// lane grid: og = lane>>3 (8 o's), jg = lane&7 (4 j's); acc[4][8].
__global__ __launch_bounds__(256, 4) void pair_kernel(
    const float* __restrict__ t2d, const float* __restrict__ proj_w,
    const float* __restrict__ leftpe, const float* __restrict__ rightpe,
    float* __restrict__ out)
{
    __shared__ float Wt[NF2D * 64];       // [k][o]
    __shared__ float aux[128];            // [0:64) wsep, [64:128) lpe
    __shared__ float xT[4][NF2D * 32];    // per-wave [k][j]

    const int tid  = threadIdx.x;
    const int blk  = blockIdx.x;          // bt*512 + i
    const int bt   = blk >> 9;
    const int i    = blk & 511;
    const int wave = tid >> 6;
    const int lane = tid & 63;
    const int og   = lane >> 3;           // 8 o's: og*8..+7
    const int jg   = lane & 7;            // 4 j's: jg*4..+3
    const int lrow = lane & 31;
    const int h    = lane >> 5;

    for (int idx = tid; idx < NF2D * 64; idx += 256) {
        int o = idx & 63, k = idx >> 6;
        Wt[idx] = proj_w[o * 109 + k];
    }
    if (tid < 64) {
        aux[tid]      = proj_w[tid * 109 + 108];   // wsep
        aux[64 + tid] = leftpe[blk * 64 + tid];    // lpe (pe folded for bt==0)
    }
    __syncthreads();

    float lp[8], wv[8];
#pragma unroll
    for (int c = 0; c < 8; ++c) {
        lp[c] = aux[64 + og * 8 + c];
        wv[c] = aux[og * 8 + c];
    }

    float* xTw = xT[wave];
    const int jbase = wave * 128;
    const float* xbase0 = t2d + ((size_t)blk * LL + jbase + lrow) * NF2D;
    const float* rbase = rightpe + (size_t)(bt << 9) * 64;
    float* obase = out + (size_t)blk * LL * KK;

    // prefetch tile 0: lane loads row (lrow), float4 indices f = h, h+2, ..., h+10
    float4 nv[6];
#pragma unroll
    for (int q = 0; q < 6; ++q) {
        if (q < 5 || h == 0) nv[q] = ((const float4*)xbase0)[h + 2 * q];
    }

    for (int t = 0; t < 4; ++t) {
        // transpose current tile into LDS (banks = lrow -> 2-way, free)
#pragma unroll
        for (int q = 0; q < 6; ++q) {
            if (q < 5 || h == 0) {
                int f = h + 2 * q;
                float4 v = nv[q];
                xTw[(4 * f + 0) * 32 + lrow] = v.x;
                xTw[(4 * f + 1) * 32 + lrow] = v.y;
                xTw[(4 * f + 2) * 32 + lrow] = v.z;
                xTw[(4 * f + 3) * 32 + lrow] = v.w;
            }
        }
        // issue next-tile loads early (HBM latency hides under compute)
        if (t < 3) {
            const float4* ns = (const float4*)(xbase0 + (size_t)(t + 1) * 32 * NF2D);
#pragma unroll
            for (int q = 0; q < 6; ++q) {
                if (q < 5 || h == 0) nv[q] = ns[h + 2 * q];
            }
        }

        float acc[4][8];
#pragma unroll
        for (int r = 0; r < 4; ++r)
#pragma unroll
            for (int c = 0; c < 8; ++c) acc[r][c] = 0.f;

#pragma unroll 4
        for (int k = 0; k < NF2D; ++k) {
            float4 a  = *(const float4*)&xTw[k * 32 + jg * 4];
            float4 b0 = *(const float4*)&Wt[k * 64 + og * 8];
            float4 b1 = *(const float4*)&Wt[k * 64 + og * 8 + 4];
            float av[4] = {a.x, a.y, a.z, a.w};
            float bv[8] = {b0.x, b0.y, b0.z, b0.w, b1.x, b1.y, b1.z, b1.w};
#pragma unroll
            for (int r = 0; r < 4; ++r)
#pragma unroll
                for (int c = 0; c < 8; ++c)
                    acc[r][c] = fmaf(av[r], bv[c], acc[r][c]);
        }

        const int j0 = jbase + t * 32 + jg * 4;
#pragma unroll
        for (int r = 0; r < 4; ++r) {
            int j = j0 + r;
            int d = i - j; d = d < 0 ? -d : d;
            float sv = __logf((float)(d + 1));
            const float4* rp = (const float4*)(rbase + (size_t)j * 64 + og * 8);
            float4 r0 = rp[0], r1 = rp[1];
            float4 o0, o1;
            o0.x = acc[r][0] + lp[0] + r0.x + sv * wv[0];
            o0.y = acc[r][1] + lp[1] + r0.y + sv * wv[1];
            o0.z = acc[r][2] + lp[2] + r0.z + sv * wv[2];
            o0.w = acc[r][3] + lp[3] + r0.w + sv * wv[3];
            o1.x = acc[r][4] + lp[4] + r1.x + sv * wv[4];
            o1.y = acc[r][5] + lp[5] + r1.y + sv * wv[5];
            o1.z = acc[r][6] + lp[6] + r1.z + sv * wv[6];
            o1.w = acc[r][7] + lp[7] + r1.w + sv * wv[7];
            float4* op = (float4*)(obase + (size_t)j * 64 + og * 8);
            op[0] = o0;
            op[1] = o1;
        }
    }
}

extern "C" void kernel_launch(void* const* d_in, const int* in_sizes, int n_in,
                              void* d_out, int out_size, void* d_ws, size_t ws_size,
                              hipStream_t stream) {
    const float* t1d = (const float*)d_in[0];
    const float* t2d = (const float*)d_in[1];
    const float* w1d = (const float*)d_in[2];
    const float* b1d = (const float*)d_in[3];
    const float* c1w = (const float*)d_in[4];
    const float* c2w = (const float*)d_in[5];
    const float* pw  = (const float*)d_in[6];
    const float* pb  = (const float*)d_in[7];
    float* out = (float*)d_out;
    float* ws = (float*)d_ws;

    float* lpe = ws;                 // 4*512*64 = 131072 floats
    float* rpe = ws + 131072;

    tower_kernel<<<4, 512, 0, stream>>>(t1d, w1d, b1d, c1w, c2w, pw, pb, lpe, rpe);
    pair_kernel<<<2048, 256, 0, stream>>>(t2d, pw, lpe, rpe, out);
}

// Round 4
// 631.280 us; speedup vs baseline: 1.0491x; 1.0491x over previous
//
#include <hip/hip_runtime.h>
#include <cstddef>

#define LL 512
#define CC 32
#define NF1D 46
#define NF2D 44
#define KK 64

__device__ __forceinline__ float elu1(float a) {
    return a > 0.f ? a : (expf(a) - 1.f);
}

// swizzled LDS word index for tower x/y arrays.
// ri = l+1 in [0,513]; row stride 32 words; XOR ic-chunk with (ri>>4)&7 so the
// 8 strips (stride 16 rows = 2KB = 0 mod 32 banks) read from distinct banks.
__device__ __forceinline__ int xw(int ri, int ic) {
    return (ri << 5) + ((((ic >> 2) ^ ((ri >> 4) & 7)) << 2) | (ic & 3));
}
__device__ __forceinline__ int xw4(int ri, int icc) {
    return (ri << 5) + ((icc ^ ((ri >> 4) & 7)) << 2);
}

// ---------------- tower kernel: 256 blocks, fully redundant per block -------
// block = (bt = blk>>6, seg = blk&63). Every block computes the ENTIRE tower
// for its bt in LDS (stats are block-local -> zero cross-block comm), then
// writes only its 8-row slice of lpe/rpe. One plain launch, no sync hazards.
__global__ __launch_bounds__(256, 1) void tower_kernel(
    const float* __restrict__ t1d, const float* __restrict__ w1d,
    const float* __restrict__ b1d, const float* __restrict__ c1w,
    const float* __restrict__ c2w, const float* __restrict__ proj_w,
    const float* __restrict__ proj_b, float* __restrict__ lpe,
    float* __restrict__ rpe)
{
    __shared__ float xs[514 * 32];      // 65792 B, rows ri=0..513 (halo 0,513)
    __shared__ float ys[514 * 32];      // 65792 B; reused: proj scratch, plL/plR
    __shared__ float wl[3072];          // conv weights, [icc][oc][d][iq]
    __shared__ float redS[33 * 32];
    __shared__ float redQ[33 * 32];
    __shared__ float mvs[64];

    const int tid = threadIdx.x;
    const int bt  = blockIdx.x >> 6;
    const int seg = blockIdx.x & 63;
    const int oc8 = tid & 7;            // conv: 4 ocs {oc8, +8, +16, +24}
    const int p   = tid >> 3;           // conv: l-strip [16p, 16p+16)

    // zero halo rows (never written again)
    if (tid < 128) {
        int w = tid & 31;
        int ri = (tid & 32) ? 513 : 0;
        if (tid < 64) xs[ri * 32 + w] = 0.f;
        else          ys[ri * 32 + w] = 0.f;
    }
    // stage stage-0 conv weights: wl[(ic>>2)*384 + oc*12 + d*4 + (ic&3)]
    for (int t = tid; t < 3072; t += 256) {
        int o = t / 96, rem = t - o * 96;
        int ic = rem / 3, d = rem - ic * 3;
        wl[(ic >> 2) * 384 + o * 12 + d * 4 + (ic & 3)] = c1w[t];
    }

    // ---- initial projection: xs = proj(t1d) + b, chunked via ys scratch ----
    {
        const int c = tid & 31;
        float wp[46];
#pragma unroll
        for (int f = 0; f < 46; ++f) wp[f] = w1d[c * 46 + f];
        const float bb = b1d[c];
        float* ts = ys + 64;            // rows 2.. of ys: clear of halo row 0
        for (int ch = 0; ch < 32; ++ch) {
            const int l0c = ch << 4;
            __syncthreads();
            for (int t = tid; t < 736; t += 256) {
                int r = t / 46, f = t - r * 46;
                ts[r * 48 + f] = t1d[((size_t)(bt * LL + l0c + r)) * 46 + f];
            }
            __syncthreads();
            int rr = (tid >> 5) << 1;
#pragma unroll
            for (int u = 0; u < 2; ++u) {
                const float2* row = (const float2*)(ts + (rr + u) * 48);
                float a = bb;
#pragma unroll
                for (int f2 = 0; f2 < 23; ++f2) {
                    float2 v = row[f2];
                    a = fmaf(v.x, wp[2 * f2], a);
                    a = fmaf(v.y, wp[2 * f2 + 1], a);
                }
                xs[xw(l0c + rr + u + 1, c)] = a;
            }
        }
    }
    __syncthreads();

    // ---- 8 conv stages (4 resblocks x {conv1, conv2}) ----
    const int lb = p << 4;
    for (int s = 0; s < 8; ++s) {
        const float* src = (s & 1) ? ys : xs;
        float acc[4][16];
#pragma unroll
        for (int m = 0; m < 4; ++m)
#pragma unroll
            for (int i2 = 0; i2 < 16; ++i2) acc[m][i2] = 0.f;

        for (int icc = 0; icc < 8; ++icc) {
            float4 wv0[4], wv1[4], wv2[4];
#pragma unroll
            for (int m = 0; m < 4; ++m) {
                const float* wb_ = wl + icc * 384 + (oc8 + 8 * m) * 12;
                wv0[m] = *(const float4*)(wb_);
                wv1[m] = *(const float4*)(wb_ + 4);
                wv2[m] = *(const float4*)(wb_ + 8);
            }
            float4 x0 = *(const float4*)&src[xw4(lb, icc)];
            float4 x1 = *(const float4*)&src[xw4(lb + 1, icc)];
#pragma unroll
            for (int i2 = 0; i2 < 16; ++i2) {
                float4 x2 = *(const float4*)&src[xw4(lb + 2 + i2, icc)];
#pragma unroll
                for (int m = 0; m < 4; ++m) {
                    float a = acc[m][i2];
                    a = fmaf(x0.x, wv0[m].x, a);
                    a = fmaf(x0.y, wv0[m].y, a);
                    a = fmaf(x0.z, wv0[m].z, a);
                    a = fmaf(x0.w, wv0[m].w, a);
                    a = fmaf(x1.x, wv1[m].x, a);
                    a = fmaf(x1.y, wv1[m].y, a);
                    a = fmaf(x1.z, wv1[m].z, a);
                    a = fmaf(x1.w, wv1[m].w, a);
                    a = fmaf(x2.x, wv2[m].x, a);
                    a = fmaf(x2.y, wv2[m].y, a);
                    a = fmaf(x2.z, wv2[m].z, a);
                    a = fmaf(x2.w, wv2[m].w, a);
                    acc[m][i2] = a;
                }
                x0 = x1; x1 = x2;
            }
        }
        // block-local instance-norm stats (full L is local!)
#pragma unroll
        for (int m = 0; m < 4; ++m) {
            float sSum = 0.f, sSq = 0.f;
#pragma unroll
            for (int i2 = 0; i2 < 16; ++i2) {
                sSum += acc[m][i2];
                sSq = fmaf(acc[m][i2], acc[m][i2], sSq);
            }
            redS[(oc8 + 8 * m) * 33 + p] = sSum;
            redQ[(oc8 + 8 * m) * 33 + p] = sSq;
        }
        __syncthreads();
        if (tid < 32) {
            float S = 0.f, Q = 0.f;
#pragma unroll
            for (int k2 = 0; k2 < 32; ++k2) {
                S += redS[tid * 33 + k2];
                Q += redQ[tid * 33 + k2];
            }
            float m_ = S * (1.f / 512.f);
            float v_ = Q * (1.f / 512.f) - m_ * m_;
            mvs[tid] = m_;
            mvs[32 + tid] = rsqrtf(v_ + 1e-5f);
        }
        if (s < 7) {
            // stage next conv weights (conv reads of wl completed at barrier)
            const float* cw = ((s + 1) & 1) ? (c2w + ((s + 1) >> 1) * 3072)
                                            : (c1w + ((s + 1) >> 1) * 3072);
            for (int t = tid; t < 3072; t += 256) {
                int o = t / 96, rem = t - o * 96;
                int ic = rem / 3, d = rem - ic * 3;
                wl[(ic >> 2) * 384 + o * 12 + d * 4 + (ic & 3)] = cw[t];
            }
        } else {
            // stage epilogue Wl/Wr into ys (free after this stage's conv)
            for (int t = tid; t < 2048; t += 256) {
                int o = t >> 5, c2 = t & 31;
                ys[c2 * 64 + (o ^ c2)]        = proj_w[o * 109 + 44 + c2];
                ys[2048 + c2 * 64 + (o ^ c2)] = proj_w[o * 109 + 76 + c2];
            }
        }
        __syncthreads();
        if (!(s & 1)) {
            // conv1 out: ys = elu(norm(z))
#pragma unroll
            for (int m = 0; m < 4; ++m) {
                int oc = oc8 + 8 * m;
                float mm = mvs[oc], iv = mvs[32 + oc];
#pragma unroll
                for (int i2 = 0; i2 < 16; ++i2)
                    ys[xw(lb + 1 + i2, oc)] = elu1((acc[m][i2] - mm) * iv);
            }
        } else {
            // conv2 out: xs = elu(xs + norm(z))  (also the FIN emb at s==7)
#pragma unroll
            for (int m = 0; m < 4; ++m) {
                int oc = oc8 + 8 * m;
                float mm = mvs[oc], iv = mvs[32 + oc];
#pragma unroll
                for (int i2 = 0; i2 < 16; ++i2) {
                    int a_ = xw(lb + 1 + i2, oc);
                    xs[a_] = elu1(xs[a_] + (acc[m][i2] - mm) * iv);
                }
            }
        }
        __syncthreads();
    }

    // ---- epilogue: own 8-l slice -> lpe/rpe (pe + bias folded) ----
    {
        const float C16 = 0.5756462732485115f;   // ln(10000)/16
        const int o = tid & 63;
        const int w = tid >> 6;
        const float wb2 = proj_b[o];
        const float* plL = ys;
        const float* plR = ys + 2048;
        float freq = expf(-(float)(o & 15) * C16);
        bool isSin = (o & 31) < 16;
#pragma unroll
        for (int u = 0; u < 2; ++u) {
            int l = (seg << 3) + w + (u << 2);
            float lacc = 0.f, racc = wb2;
#pragma unroll
            for (int c2 = 0; c2 < 32; ++c2) {
                float e = xs[xw(l + 1, c2)];
                lacc = fmaf(e, plL[c2 * 64 + (o ^ c2)], lacc);
                racc = fmaf(e, plR[c2 * 64 + (o ^ c2)], racc);
            }
            if (bt == 0) {
                float ang = (float)l * freq;
                float pe = isSin ? sinf(ang) : cosf(ang);
                if (o < 32) lacc += pe; else racc += pe;
            }
            size_t r = (size_t)(bt * LL + l) * 64 + o;
            lpe[r] = lacc;
            rpe[r] = racc;
        }
    }
}

// ---------------- pair kernel: 32-j tiles x4, rolling prefetch --------------
// Round-1 verified lane/store mapping (jg = lane>>3, og = lane&7). LDS 34.3 KB
// -> 3 blocks/CU at launch_bounds(256,3) = 12 waves/CU (was 8).
__global__ __launch_bounds__(256, 3) void pair_kernel(
    const float* __restrict__ t2d, const float* __restrict__ proj_w,
    const float* __restrict__ leftpe, const float* __restrict__ rightpe,
    float* __restrict__ out)
{
    __shared__ float Wt[NF2D * 64];       // [k][o]
    __shared__ float aux[128];            // [0:64) wsep, [64:128) lpe
    __shared__ float xT[4][NF2D * 32];    // per-wave [k][j-local]

    const int tid  = threadIdx.x;
    const int blk  = blockIdx.x;          // bt*512 + i
    const int bt   = blk >> 9;
    const int i    = blk & 511;
    const int wave = tid >> 6;
    const int lane = tid & 63;
    const int jg   = lane >> 3;           // 8 j-groups of 4
    const int og   = lane & 7;            // 8 o-groups of 8 (contiguous stores)
    const int lrow = lane & 31;
    const int h    = lane >> 5;

    float* xTw = xT[wave];
    const int jbase = wave * 128;
    const float* xsrc = t2d + ((size_t)blk * LL + jbase + lrow) * NF2D;

    // issue tile-0 loads first: in flight during Wt staging + barrier
    float4 nv[6];
#pragma unroll
    for (int q = 0; q < 6; ++q)
        if (q < 5 || h == 0) nv[q] = ((const float4*)xsrc)[h + 2 * q];

    for (int idx = tid; idx < NF2D * 64; idx += 256) {
        int o = idx & 63, k = idx >> 6;
        Wt[idx] = proj_w[o * 109 + k];
    }
    if (tid < 64) {
        aux[tid]      = proj_w[tid * 109 + 108];   // wsep
        aux[64 + tid] = leftpe[blk * 64 + tid];    // lpe (pe folded for bt==0)
    }
    __syncthreads();

    float lp[8], wv[8];
#pragma unroll
    for (int c = 0; c < 8; ++c) {
        lp[c] = aux[64 + og * 8 + c];
        wv[c] = aux[og * 8 + c];
    }

    const float* rbase = rightpe + (size_t)(bt << 9) * 64;
    float* obase = out + (size_t)blk * LL * KK;

    for (int t = 0; t < 4; ++t) {
        // transpose current tile regs -> LDS (banks = lrow: 2-way, free)
#pragma unroll
        for (int q = 0; q < 6; ++q) {
            if (q < 5 || h == 0) {
                int f = h + 2 * q;
                xTw[(4 * f + 0) * 32 + lrow] = nv[q].x;
                xTw[(4 * f + 1) * 32 + lrow] = nv[q].y;
                xTw[(4 * f + 2) * 32 + lrow] = nv[q].z;
                xTw[(4 * f + 3) * 32 + lrow] = nv[q].w;
            }
        }
        // prefetch next tile: HBM latency hides under this tile's compute
        float4 pv[6];
        if (t < 3) {
            const float4* ns = (const float4*)(xsrc + (size_t)(t + 1) * 32 * NF2D);
#pragma unroll
            for (int q = 0; q < 6; ++q)
                if (q < 5 || h == 0) pv[q] = ns[h + 2 * q];
        }

        float acc[4][8];
#pragma unroll
        for (int r = 0; r < 4; ++r)
#pragma unroll
            for (int c = 0; c < 8; ++c) acc[r][c] = 0.f;

#pragma unroll 4
        for (int k = 0; k < NF2D; ++k) {
            float4 a  = *(const float4*)&xTw[k * 32 + jg * 4];
            float4 b0 = *(const float4*)&Wt[k * 64 + og * 8];
            float4 b1 = *(const float4*)&Wt[k * 64 + og * 8 + 4];
            float av[4] = {a.x, a.y, a.z, a.w};
            float bv[8] = {b0.x, b0.y, b0.z, b0.w, b1.x, b1.y, b1.z, b1.w};
#pragma unroll
            for (int r = 0; r < 4; ++r)
#pragma unroll
                for (int c = 0; c < 8; ++c)
                    acc[r][c] = fmaf(av[r], bv[c], acc[r][c]);
        }

        const int j0 = jbase + t * 32 + jg * 4;
#pragma unroll
        for (int r = 0; r < 4; ++r) {
            int j = j0 + r;
            int d = i - j; d = d < 0 ? -d : d;
            float sv = __logf((float)(d + 1));
            const float4* rp = (const float4*)(rbase + (size_t)j * 64 + og * 8);
            float4 r0 = rp[0], r1 = rp[1];
            float4 o0, o1;
            o0.x = acc[r][0] + lp[0] + r0.x + sv * wv[0];
            o0.y = acc[r][1] + lp[1] + r0.y + sv * wv[1];
            o0.z = acc[r][2] + lp[2] + r0.z + sv * wv[2];
            o0.w = acc[r][3] + lp[3] + r0.w + sv * wv[3];
            o1.x = acc[r][4] + lp[4] + r1.x + sv * wv[4];
            o1.y = acc[r][5] + lp[5] + r1.y + sv * wv[5];
            o1.z = acc[r][6] + lp[6] + r1.z + sv * wv[6];
            o1.w = acc[r][7] + lp[7] + r1.w + sv * wv[7];
            float4* op = (float4*)(obase + (size_t)j * 64 + og * 8);
            op[0] = o0;
            op[1] = o1;
        }

        if (t < 3) {
#pragma unroll
            for (int q = 0; q < 6; ++q) nv[q] = pv[q];
        }
    }
}

extern "C" void kernel_launch(void* const* d_in, const int* in_sizes, int n_in,
                              void* d_out, int out_size, void* d_ws, size_t ws_size,
                              hipStream_t stream) {
    const float* t1d = (const float*)d_in[0];
    const float* t2d = (const float*)d_in[1];
    const float* w1d = (const float*)d_in[2];
    const float* b1d = (const float*)d_in[3];
    const float* c1w = (const float*)d_in[4];
    const float* c2w = (const float*)d_in[5];
    const float* pw  = (const float*)d_in[6];
    const float* pb  = (const float*)d_in[7];
    float* out = (float*)d_out;
    float* ws = (float*)d_ws;

    float* lpe = ws;                 // 4*512*64 = 131072 floats
    float* rpe = ws + 131072;

    tower_kernel<<<256, 256, 0, stream>>>(t1d, w1d, b1d, c1w, c2w, pw, pb,
                                          lpe, rpe);
    pair_kernel<<<2048, 256, 0, stream>>>(t2d, pw, lpe, rpe, out);
}